// Round 6
// baseline (236.868 us; speedup 1.0000x reference)
//
#include <hip/hip_runtime.h>
#include <math.h>

#define VV 128000
#define NB 128
#define PP 2048
#define OO 256
#define GW 4000       // VV/32 words per row bitmask

#define S   8         // chunks per row
#define CH  16000     // tokens per chunk
#define CW  500       // CH/32 words
#define NT0 512
#define NT1 512
#define CAP 512       // survivor slots per chunk (global ws)
#define HS1 512       // hash slots

#define NT2 512
#define MC  2048      // k2 compacted sort size

#define BIG_NEG_F (-1e30f)
#define PAD_KEY 0x007FFFFF80000000ULL  // packkey(-inf, 0x7fffffff)
#define LOG2E 1.4426950408889634f

__device__ __forceinline__ unsigned long long packkey(float f, int idx) {
  unsigned int b = __float_as_uint(f);
  unsigned int mf = (b & 0x80000000u) ? ~b : (b | 0x80000000u);
  return ((unsigned long long)mf << 32) | (unsigned long long)(unsigned int)(~(unsigned int)idx);
}
__device__ __forceinline__ float unpack_val(unsigned long long k) {
  unsigned int mf = (unsigned int)(k >> 32);
  unsigned int b = (mf & 0x80000000u) ? (mf & 0x7fffffffu) : ~mf;
  return __uint_as_float(b);
}
__device__ __forceinline__ int unpack_idx(unsigned long long k) {
  return (int)(~(unsigned int)(k & 0xffffffffu));
}
__device__ __forceinline__ float ulp_down(float f, int n) {
  unsigned int b = __float_as_uint(f);
  unsigned int m = (b & 0x80000000u) ? ~b : (b | 0x80000000u);
  m -= (unsigned int)n;
  unsigned int r = (m & 0x80000000u) ? (m & 0x7fffffffu) : ~m;
  return __uint_as_float(r);
}

// in-register descending bitonic sort of 64 values across a wave.
// lane L ends holding the (L+1)-th largest (validated exact in rounds 5).
__device__ __forceinline__ float wave_sort64_desc(float v, int lane) {
  for (int k = 2; k <= 64; k <<= 1) {
    for (int j = k >> 1; j > 0; j >>= 1) {
      float o = __shfl_xor(v, j, 64);
      bool smaller = (lane & j) == 0;
      bool dir = (lane & k) == 0;
      bool keepmax = (smaller == dir);
      v = keepmax ? fmaxf(v, o) : fminf(v, o);
    }
  }
  return v;
}

template <int N, int T>
__device__ __forceinline__ void bitonic_desc_u64(unsigned long long* a, int tid) {
  for (int k = 2; k <= N; k <<= 1) {
    for (int j = k >> 1; j > 0; j >>= 1) {
      for (int i = tid; i < N; i += T) {
        int ixj = i ^ j;
        if (ixj > i) {
          unsigned long long x = a[i], y = a[ixj];
          bool up = (i & k) == 0;
          if ((x < y) == up) { a[i] = y; a[ixj] = x; }
        }
      }
      __syncthreads();
    }
  }
}

// ---------------- kernel 0: per-row global bitmasks + count hash ------------
__global__ __launch_bounds__(NT0)
void k0_build(const int* __restrict__ prompt_ids,
              const int* __restrict__ output_ids,
              unsigned int* __restrict__ ws_pb,
              unsigned int* __restrict__ ws_ob,
              int* __restrict__ ws_hk,
              int* __restrict__ ws_hv)
{
  __shared__ int hkey[HS1];
  __shared__ int hval[HS1];
  const int row = blockIdx.x;
  const int tid = threadIdx.x;

  unsigned int* pb = ws_pb + (size_t)row * GW;
  unsigned int* ob = ws_ob + (size_t)row * GW;
  uint4* pb4 = (uint4*)pb;
  uint4* ob4 = (uint4*)ob;
  uint4 z; z.x = 0u; z.y = 0u; z.z = 0u; z.w = 0u;
  for (int i = tid; i < GW / 4; i += NT0) { pb4[i] = z; ob4[i] = z; }
  for (int i = tid; i < HS1; i += NT0) { hkey[i] = -1; hval[i] = 0; }
  __syncthreads();

  const int4* pr4 = (const int4*)(prompt_ids + (size_t)row * PP);
  for (int i = tid; i < PP / 4; i += NT0) {
    int4 tv = pr4[i];
    atomicOr(&pb[tv.x >> 5], 1u << (tv.x & 31));
    atomicOr(&pb[tv.y >> 5], 1u << (tv.y & 31));
    atomicOr(&pb[tv.z >> 5], 1u << (tv.z & 31));
    atomicOr(&pb[tv.w >> 5], 1u << (tv.w & 31));
  }
  for (int i = tid; i < OO; i += NT0) {
    int tok = output_ids[row * OO + i];
    atomicOr(&ob[tok >> 5], 1u << (tok & 31));
    unsigned int h = ((unsigned int)tok * 2654435761u) >> 23;
    for (;;) {
      int k = hkey[h];
      if (k == tok) { atomicAdd(&hval[h], 1); break; }
      if (k == -1) {
        int prev = atomicCAS(&hkey[h], -1, tok);
        if (prev == -1 || prev == tok) { atomicAdd(&hval[h], 1); break; }
        continue;
      }
      h = (h + 1) & (HS1 - 1);
    }
  }
  __syncthreads();
  for (int i = tid; i < HS1; i += NT0) {
    ws_hk[row * HS1 + i] = hkey[i];
    ws_hv[row * HS1 + i] = hval[i];
  }
}

// ---------------- kernel 1: per-chunk penalize + exp2-sum + survivor select --
__global__ __launch_bounds__(NT1)
void k1_select(const float* __restrict__ logits,
               const int* __restrict__ stop_ids,
               const int* __restrict__ min_tokens,
               const float* __restrict__ presence_p,
               const float* __restrict__ frequency_p,
               const float* __restrict__ repetition_p,
               const float* __restrict__ temperature,
               const unsigned int* __restrict__ ws_pb,
               const unsigned int* __restrict__ ws_ob,
               const int* __restrict__ ws_hk,
               const int* __restrict__ ws_hv,
               unsigned long long* __restrict__ ws_cand,
               float* __restrict__ ws_sum,
               int* __restrict__ ws_cnt)
{
#pragma clang fp contract(off)
  __shared__ unsigned int pbits[CW];
  __shared__ unsigned int obits[CW];
  __shared__ int hkey[HS1];
  __shared__ int hval[HS1];
  __shared__ float wtau[NT1 / 64];
  __shared__ float wsum[NT1 / 64];
  __shared__ float tau_sh;
  __shared__ int cnt_sh;

  const int chunk = blockIdx.x;
  const int row   = blockIdx.y;
  const int tid   = threadIdx.x;
  const int lane  = tid & 63;
  const int base  = chunk * CH;

  const float fp  = frequency_p[row];
  const float pp  = presence_p[row];
  const float rp  = repetition_p[row];
  const float inv_rp = 1.0f / rp;
  const float tmp = temperature[row];
  const float t   = (tmp < 1e-5f) ? 1.0f : tmp;
  const float c2  = LOG2E / t;
  const bool need = min_tokens[row] > OO;
  const int s0 = stop_ids[row * 4 + 0];
  const int s1 = stop_ids[row * 4 + 1];
  const int s2 = stop_ids[row * 4 + 2];
  const int s3 = stop_ids[row * 4 + 3];
  const bool anystop = need &&
      (((unsigned)(s0 - base) < CH) || ((unsigned)(s1 - base) < CH) ||
       ((unsigned)(s2 - base) < CH) || ((unsigned)(s3 - base) < CH));

  // load per-row structures (built by k0)
  const unsigned int* pbg = ws_pb + (size_t)row * GW + chunk * CW;
  const unsigned int* obg = ws_ob + (size_t)row * GW + chunk * CW;
  for (int i = tid; i < CW; i += NT1) { pbits[i] = pbg[i]; obits[i] = obg[i]; }
  for (int i = tid; i < HS1; i += NT1) {
    hkey[i] = ws_hk[row * HS1 + i];
    hval[i] = ws_hv[row * HS1 + i];
  }
  if (tid == 0) cnt_sh = 0;
  __syncthreads();

  const float* __restrict__ lrow = logits + (size_t)row * VV + base;
  const int l0 = (0 * NT1 + tid) << 3;
  const int l1 = (1 * NT1 + tid) << 3;
  const int l2 = (2 * NT1 + tid) << 3;
  const int l3 = (3 * NT1 + tid) << 3;
  const bool v3 = l3 < CH;

  // ---- phase A: all loads in flight, then process ----
  float4 A0 = *(const float4*)(lrow + l0);
  float4 B0 = *(const float4*)(lrow + l0 + 4);
  float4 A1 = *(const float4*)(lrow + l1);
  float4 B1 = *(const float4*)(lrow + l1 + 4);
  float4 A2 = *(const float4*)(lrow + l2);
  float4 B2 = *(const float4*)(lrow + l2 + 4);
  float4 A3, B3;
  if (v3) { A3 = *(const float4*)(lrow + l3); B3 = *(const float4*)(lrow + l3 + 4); }

  float mx = -INFINITY;
  float esum = 0.0f;

  auto processA = [&](int li, float4 xa, float4 xb) {
    unsigned int w  = (unsigned)li >> 5;
    unsigned int sh = (unsigned)li & 31u;
    unsigned int pm8 = (pbits[w] >> sh) & 255u;
    unsigned int om8 = (obits[w] >> sh) & 255u;
    float xs[8] = {xa.x, xa.y, xa.z, xa.w, xb.x, xb.y, xb.z, xb.w};
#pragma unroll
    for (int e = 0; e < 8; ++e) {
      float xp = xs[e];
      int v = base + li + e;
      if (anystop && ((v == s0) | (v == s1) | (v == s2) | (v == s3)))
        xp = BIG_NEG_F;
      if ((pm8 | om8) & (1u << e)) {
        xp = (xp > 0.0f) ? (xp * inv_rp) : (xp * rp);
        if ((om8 >> e) & 1u) {
          float cnt = 0.0f;
          unsigned int h = ((unsigned int)v * 2654435761u) >> 23;
          for (;;) {
            int k = hkey[h];
            if (k == -1) break;
            if (k == v) { cnt = (float)hval[h]; break; }
            h = (h + 1) & (HS1 - 1);
          }
          xp = xp - fp * cnt - pp;
        }
      }
      mx = fmaxf(mx, xp);
      esum += exp2f(xp * c2);
    }
  };

  processA(l0, A0, B0);
  processA(l1, A1, B1);
  processA(l2, A2, B2);
  if (v3) processA(l3, A3, B3);

  // wave-level reductions (register only)
  float ss = esum;
#pragma unroll
  for (int off = 32; off > 0; off >>= 1) ss += __shfl_down(ss, off, 64);
  if (lane == 0) wsum[tid >> 6] = ss;

  float srt = wave_sort64_desc(mx, lane);
  if (lane == 7) wtau[tid >> 6] = srt;   // wave's 8th-largest thread-max
  __syncthreads();

  if (tid == 0) {
    float tau = wtau[0];
#pragma unroll
    for (int w = 1; w < NT1 / 64; ++w) tau = fminf(tau, wtau[w]);
    tau_sh = ulp_down(tau, 16);          // slack covers mul-vs-div approx
    float sacc = 0.0f;
#pragma unroll
    for (int w = 0; w < NT1 / 64; ++w) sacc += wsum[w];
    ws_sum[row * S + chunk] = sacc;
  }
  __syncthreads();
  const float taueff = tau_sh;

  // ---- phase B: re-stream (L2/L3-warm); raw-filter, exact recompute, append
  unsigned long long* __restrict__ wc = ws_cand + ((size_t)row * S + chunk) * CAP;

  A0 = *(const float4*)(lrow + l0); B0 = *(const float4*)(lrow + l0 + 4);
  A1 = *(const float4*)(lrow + l1); B1 = *(const float4*)(lrow + l1 + 4);
  A2 = *(const float4*)(lrow + l2); B2 = *(const float4*)(lrow + l2 + 4);
  if (v3) { A3 = *(const float4*)(lrow + l3); B3 = *(const float4*)(lrow + l3 + 4); }

  auto processB = [&](int li, float4 xa, float4 xb) {
    float xs[8] = {xa.x, xa.y, xa.z, xa.w, xb.x, xb.y, xb.z, xb.w};
#pragma unroll
    for (int e = 0; e < 8; ++e) {
      float x = xs[e];
      if (x >= taueff) {                 // raw >= penalized -> safe superset
        int v = base + li + e;
        int ll = li + e;
        if (anystop && ((v == s0) | (v == s1) | (v == s2) | (v == s3)))
          x = fminf(x, BIG_NEG_F);
        bool pm = (pbits[(unsigned)ll >> 5] >> ((unsigned)ll & 31u)) & 1u;
        bool om = (obits[(unsigned)ll >> 5] >> ((unsigned)ll & 31u)) & 1u;
        float cnt = 0.0f;
        if (om) {
          unsigned int h = ((unsigned int)v * 2654435761u) >> 23;
          for (;;) {
            int k = hkey[h];
            if (k == -1) break;
            if (k == v) { cnt = (float)hval[h]; break; }
            h = (h + 1) & (HS1 - 1);
          }
        }
        if (pm || om) x = (x > 0.0f) ? (x / rp) : (x * rp);
        x = x - fp * cnt;
        if (om) x = x - pp;
        if (x >= taueff) {
          float xd = x / t;              // exact reference finalist value
          int p = atomicAdd(&cnt_sh, 1);
          if (p < CAP) wc[p] = packkey(xd, v);
        }
      }
    }
  };

  processB(l0, A0, B0);
  processB(l1, A1, B1);
  processB(l2, A2, B2);
  if (v3) processB(l3, A3, B3);

  __syncthreads();
  if (tid == 0) ws_cnt[row * S + chunk] = (cnt_sh < CAP) ? cnt_sh : CAP;
}

// ---------------- kernel 2: compact + merge + finalize ----------------------
__global__ __launch_bounds__(NT2)
void k2_finalize(const float* __restrict__ temperature,
                 const int* __restrict__ top_k,
                 const float* __restrict__ top_p,
                 const float* __restrict__ noise,
                 const unsigned long long* __restrict__ ws_cand,
                 const float* __restrict__ ws_sum,
                 const int* __restrict__ ws_cnt,
                 float* __restrict__ out, int K)
{
#pragma clang fp contract(off)
  __shared__ unsigned long long cand[MC];
  __shared__ int offs[S + 1];
  __shared__ float sv[64];
  __shared__ int   si[64];
  __shared__ float se[64];
  __shared__ float gv[64];

  const int row = blockIdx.x;
  const int tid = threadIdx.x;

  const float tmp = temperature[row];
  const float t   = (tmp < 1e-5f) ? 1.0f : tmp;
  const int   tk  = top_k[row];
  const float tpv = top_p[row];

  if (tid == 0) {
    int o = 0;
    for (int c = 0; c < S; ++c) {
      offs[c] = o;
      int cc = ws_cnt[row * S + c];
      o += (cc < CAP) ? cc : CAP;
    }
    offs[S] = (o < MC) ? o : MC;
  }
  __syncthreads();
  const int total = offs[S];

  for (int g = tid; g < MC; g += NT2) {
    unsigned long long v = PAD_KEY;
    if (g < total) {
      int c = 0;
      while (c < S - 1 && g >= offs[c + 1]) c++;
      int i = g - offs[c];
      v = ws_cand[((size_t)row * S + c) * CAP + i];
    }
    cand[g] = v;
  }
  __syncthreads();

  bitonic_desc_u64<MC, NT2>(cand, tid);

  if (tid < 64) {
    unsigned long long kk = cand[tid];
    float val = unpack_val(kk);
    int   idx = unpack_idx(kk);
    float m = unpack_val(cand[0]);
    sv[tid] = val;
    si[tid] = idx;
    bool ok = (unsigned)idx < VV;
    float u = ok ? noise[(size_t)row * VV + idx] : 0.5f;
    float g = -logf(-logf(u));
    se[tid] = expf(val - m);
    gv[tid] = val / t + g;
  }
  __syncthreads();

  if (tid == 0) {
    float Ssum = 0.0f;
    for (int c = 0; c < S; c++) Ssum += ws_sum[row * S + c];
    const float m = sv[0];
    const float Z = Ssum * exp2f(-m * LOG2E);   // full-row softmax denominator

    int keff = (tk < 1) ? 64 : (tk < 64 ? tk : 64);

    float cum = 0.0f;
    int nk = 0;
    for (int j = 0; j < 64; j++) {
      if (j >= keff) break;
      if (!(cum < tpv)) break;
      nk++;
      cum += se[j] / Z;
    }

    float Zk = 0.0f;
    for (int j = 0; j < nk; j++) Zk += se[j];
    const float logZk = logf(Zk);

    float bv = -INFINITY; int bi = 0x7fffffff;
    for (int j = 0; j < nk; j++) {
      float val = gv[j];
      if (val > bv || (val == bv && si[j] < bi)) { bv = val; bi = si[j]; }
    }
    const int samp = (tmp < 1e-5f) ? si[0] : bi;
    out[row] = (float)samp;

    unsigned long long bm0 = 0ull, bm1 = 0ull;
    for (int j = 0; j < nk; j++) {
      int ix = si[j];
      if (ix < 64) bm0 |= 1ull << ix;
      else if (ix < 128) bm1 |= 1ull << (ix - 64);
    }
    int fi = 0;
    for (int j = 0; j < K; j++) {
      float lp; int ix;
      if (j < nk) {
        lp = (sv[j] - m) - logZk;
        ix = si[j];
      } else {
        while ((fi < 64) ? ((bm0 >> fi) & 1ull) : ((bm1 >> (fi - 64)) & 1ull)) fi++;
        ix = fi; fi++;
        lp = BIG_NEG_F;
      }
      out[NB + row * K + j]            = lp;
      out[NB + NB * K + row * K + j]   = (float)ix;
    }
  }
}

extern "C" void kernel_launch(void* const* d_in, const int* in_sizes, int n_in,
                              void* d_out, int out_size, void* d_ws, size_t ws_size,
                              hipStream_t stream) {
  const float* logits = (const float*)d_in[0];
  const int*   prompt = (const int*)d_in[1];
  const int*   outids = (const int*)d_in[2];
  const int*   stop   = (const int*)d_in[3];
  const int*   mint   = (const int*)d_in[4];
  const float* pres   = (const float*)d_in[5];
  const float* freq   = (const float*)d_in[6];
  const float* rep    = (const float*)d_in[7];
  const float* temp   = (const float*)d_in[8];
  const int*   topk   = (const int*)d_in[9];
  const float* topp   = (const float*)d_in[10];
  const float* noise  = (const float*)d_in[11];

  int B_ = in_sizes[4];                     // 128
  int K_ = (out_size - B_) / (2 * B_);      // 20

  // workspace layout (all 16B-aligned)
  unsigned long long* ws_cand = (unsigned long long*)d_ws;        // NB*S*CAP u64 = 4 MB
  unsigned int* ws_pb = (unsigned int*)(ws_cand + (size_t)NB * S * CAP);   // NB*GW = 2 MB
  unsigned int* ws_ob = ws_pb + (size_t)NB * GW;                  // 2 MB
  int* ws_hk = (int*)(ws_ob + (size_t)NB * GW);                   // NB*HS1
  int* ws_hv = ws_hk + (size_t)NB * HS1;
  float* ws_sum = (float*)(ws_hv + (size_t)NB * HS1);             // NB*S
  int* ws_cnt = (int*)(ws_sum + (size_t)NB * S);                  // NB*S

  k0_build<<<B_, NT0, 0, stream>>>(prompt, outids, ws_pb, ws_ob, ws_hk, ws_hv);
  dim3 g1(S, B_);
  k1_select<<<g1, NT1, 0, stream>>>(logits, stop, mint, pres, freq, rep, temp,
                                    ws_pb, ws_ob, ws_hk, ws_hv,
                                    ws_cand, ws_sum, ws_cnt);
  k2_finalize<<<B_, NT2, 0, stream>>>(temp, topk, topp, noise,
                                      ws_cand, ws_sum, ws_cnt,
                                      (float*)d_out, K_);
}

// Round 7
// 211.708 us; speedup vs baseline: 1.1188x; 1.1188x over previous
//
#include <hip/hip_runtime.h>
#include <math.h>

#define VV 128000
#define NB 128
#define PP 2048
#define OO 256
#define GW 4000       // VV/32 words per row bitmask

#define S   8         // chunks per row
#define CH  16000     // tokens per chunk
#define CW  500       // CH/32 words
#define NT0 512
#define NT1 512
#define CAP 512       // LDS survivor slots per chunk
#define HS1 512       // hash slots

#define NT2 256

#define BIG_NEG_F (-1e30f)
#define PAD_KEY 0x007FFFFF80000000ULL  // packkey(-inf, 0x7fffffff)
#define LOG2E 1.4426950408889634f

__device__ __forceinline__ unsigned long long packkey(float f, int idx) {
  unsigned int b = __float_as_uint(f);
  unsigned int mf = (b & 0x80000000u) ? ~b : (b | 0x80000000u);
  return ((unsigned long long)mf << 32) | (unsigned long long)(unsigned int)(~(unsigned int)idx);
}
__device__ __forceinline__ float unpack_val(unsigned long long k) {
  unsigned int mf = (unsigned int)(k >> 32);
  unsigned int b = (mf & 0x80000000u) ? (mf & 0x7fffffffu) : ~mf;
  return __uint_as_float(b);
}
__device__ __forceinline__ int unpack_idx(unsigned long long k) {
  return (int)(~(unsigned int)(k & 0xffffffffu));
}
__device__ __forceinline__ float ulp_down(float f, int n) {
  unsigned int b = __float_as_uint(f);
  unsigned int m = (b & 0x80000000u) ? ~b : (b | 0x80000000u);
  m -= (unsigned int)n;
  unsigned int r = (m & 0x80000000u) ? (m & 0x7fffffffu) : ~m;
  return __uint_as_float(r);
}

// in-register descending bitonic sort across a wave (lane L -> (L+1)-th largest)
__device__ __forceinline__ float wave_sort64_desc(float v, int lane) {
  for (int k = 2; k <= 64; k <<= 1) {
    for (int j = k >> 1; j > 0; j >>= 1) {
      float o = __shfl_xor(v, j, 64);
      bool smaller = (lane & j) == 0;
      bool dir = (lane & k) == 0;
      v = (smaller == dir) ? fmaxf(v, o) : fminf(v, o);
    }
  }
  return v;
}
__device__ __forceinline__ unsigned long long wave_sort64_desc_u64(unsigned long long v, int lane) {
  for (int k = 2; k <= 64; k <<= 1) {
    for (int j = k >> 1; j > 0; j >>= 1) {
      unsigned long long o = __shfl_xor(v, j, 64);
      bool smaller = (lane & j) == 0;
      bool dir = (lane & k) == 0;
      unsigned long long mx = (v > o) ? v : o;
      unsigned long long mn = (v > o) ? o : v;
      v = (smaller == dir) ? mx : mn;
    }
  }
  return v;
}
// merge two sorted-desc 64-runs (v = this wave's run, B = other run in LDS),
// keep top-64 sorted desc. Exact on packed keys (ties included).
__device__ __forceinline__ unsigned long long merge_top64(unsigned long long v,
                                                          const unsigned long long* B,
                                                          int lane) {
  unsigned long long b = B[63 - lane];
  v = (v > b) ? v : b;                  // bitonic top-64 of the union
  for (int j = 32; j > 0; j >>= 1) {    // bitonic clean, descending
    unsigned long long o = __shfl_xor(v, j, 64);
    bool hi = (lane & j) == 0;
    unsigned long long mx = (v > o) ? v : o;
    unsigned long long mn = (v > o) ? o : v;
    v = hi ? mx : mn;
  }
  return v;
}

// ---------------- kernel 0: per-row global bitmasks + count hash ------------
__global__ __launch_bounds__(NT0)
void k0_build(const int* __restrict__ prompt_ids,
              const int* __restrict__ output_ids,
              unsigned int* __restrict__ ws_pb,
              unsigned int* __restrict__ ws_ob,
              int* __restrict__ ws_hk,
              int* __restrict__ ws_hv)
{
  __shared__ int hkey[HS1];
  __shared__ int hval[HS1];
  const int row = blockIdx.x;
  const int tid = threadIdx.x;

  unsigned int* pb = ws_pb + (size_t)row * GW;
  unsigned int* ob = ws_ob + (size_t)row * GW;
  uint4* pb4 = (uint4*)pb;
  uint4* ob4 = (uint4*)ob;
  uint4 z; z.x = 0u; z.y = 0u; z.z = 0u; z.w = 0u;
  for (int i = tid; i < GW / 4; i += NT0) { pb4[i] = z; ob4[i] = z; }
  for (int i = tid; i < HS1; i += NT0) { hkey[i] = -1; hval[i] = 0; }
  __syncthreads();

  const int4* pr4 = (const int4*)(prompt_ids + (size_t)row * PP);
  for (int i = tid; i < PP / 4; i += NT0) {
    int4 tv = pr4[i];
    atomicOr(&pb[tv.x >> 5], 1u << (tv.x & 31));
    atomicOr(&pb[tv.y >> 5], 1u << (tv.y & 31));
    atomicOr(&pb[tv.z >> 5], 1u << (tv.z & 31));
    atomicOr(&pb[tv.w >> 5], 1u << (tv.w & 31));
  }
  for (int i = tid; i < OO; i += NT0) {
    int tok = output_ids[row * OO + i];
    atomicOr(&ob[tok >> 5], 1u << (tok & 31));
    unsigned int h = ((unsigned int)tok * 2654435761u) >> 23;
    for (;;) {
      int k = hkey[h];
      if (k == tok) { atomicAdd(&hval[h], 1); break; }
      if (k == -1) {
        int prev = atomicCAS(&hkey[h], -1, tok);
        if (prev == -1 || prev == tok) { atomicAdd(&hval[h], 1); break; }
        continue;
      }
      h = (h + 1) & (HS1 - 1);
    }
  }
  __syncthreads();
  for (int i = tid; i < HS1; i += NT0) {
    ws_hk[row * HS1 + i] = hkey[i];
    ws_hv[row * HS1 + i] = hval[i];
  }
}

// ------- kernel 1: per-chunk penalize + exp2-sum + exact sorted top-64 ------
__global__ __launch_bounds__(NT1)
void k1_select(const float* __restrict__ logits,
               const int* __restrict__ stop_ids,
               const int* __restrict__ min_tokens,
               const float* __restrict__ presence_p,
               const float* __restrict__ frequency_p,
               const float* __restrict__ repetition_p,
               const float* __restrict__ temperature,
               const unsigned int* __restrict__ ws_pb,
               const unsigned int* __restrict__ ws_ob,
               const int* __restrict__ ws_hk,
               const int* __restrict__ ws_hv,
               unsigned long long* __restrict__ ws_top,
               float* __restrict__ ws_sum)
{
#pragma clang fp contract(off)
  __shared__ unsigned int pbits[CW];
  __shared__ unsigned int obits[CW];
  __shared__ int hkey[HS1];
  __shared__ int hval[HS1];
  __shared__ unsigned long long cand[CAP];
  __shared__ unsigned long long mbuf[4 * 64];
  __shared__ float wtau[NT1 / 64];
  __shared__ float wsum[NT1 / 64];
  __shared__ float tau_sh;
  __shared__ int cnt_sh;

  const int chunk = blockIdx.x;
  const int row   = blockIdx.y;
  const int tid   = threadIdx.x;
  const int lane  = tid & 63;
  const int wv    = tid >> 6;
  const int base  = chunk * CH;

  const float fp  = frequency_p[row];
  const float pp  = presence_p[row];
  const float rp  = repetition_p[row];
  const float inv_rp = 1.0f / rp;
  const float tmp = temperature[row];
  const float t   = (tmp < 1e-5f) ? 1.0f : tmp;
  const float c2  = LOG2E / t;
  const bool need = min_tokens[row] > OO;
  const int s0 = stop_ids[row * 4 + 0];
  const int s1 = stop_ids[row * 4 + 1];
  const int s2 = stop_ids[row * 4 + 2];
  const int s3 = stop_ids[row * 4 + 3];
  const bool anystop = need &&
      (((unsigned)(s0 - base) < CH) || ((unsigned)(s1 - base) < CH) ||
       ((unsigned)(s2 - base) < CH) || ((unsigned)(s3 - base) < CH));

  const unsigned int* pbg = ws_pb + (size_t)row * GW + chunk * CW;
  const unsigned int* obg = ws_ob + (size_t)row * GW + chunk * CW;
  for (int i = tid; i < CW; i += NT1) { pbits[i] = pbg[i]; obits[i] = obg[i]; }
  for (int i = tid; i < HS1; i += NT1) {
    hkey[i] = ws_hk[row * HS1 + i];
    hval[i] = ws_hv[row * HS1 + i];
  }
  if (tid == 0) cnt_sh = 0;
  __syncthreads();

  const float* __restrict__ lrow = logits + (size_t)row * VV + base;
  const int l0 = (0 * NT1 + tid) << 3;
  const int l1 = (1 * NT1 + tid) << 3;
  const int l2 = (2 * NT1 + tid) << 3;
  const int l3 = (3 * NT1 + tid) << 3;
  const bool v3 = l3 < CH;

  // ---- phase A: all loads in flight, then process ----
  float4 A0 = *(const float4*)(lrow + l0);
  float4 B0 = *(const float4*)(lrow + l0 + 4);
  float4 A1 = *(const float4*)(lrow + l1);
  float4 B1 = *(const float4*)(lrow + l1 + 4);
  float4 A2 = *(const float4*)(lrow + l2);
  float4 B2 = *(const float4*)(lrow + l2 + 4);
  float4 A3, B3;
  if (v3) { A3 = *(const float4*)(lrow + l3); B3 = *(const float4*)(lrow + l3 + 4); }

  float mx = -INFINITY;
  float esum = 0.0f;

  auto processA = [&](int li, float4 xa, float4 xb) {
    unsigned int w  = (unsigned)li >> 5;
    unsigned int sh = (unsigned)li & 31u;
    unsigned int pm8 = (pbits[w] >> sh) & 255u;
    unsigned int om8 = (obits[w] >> sh) & 255u;
    float xs[8] = {xa.x, xa.y, xa.z, xa.w, xb.x, xb.y, xb.z, xb.w};
#pragma unroll
    for (int e = 0; e < 8; ++e) {
      float xp = xs[e];
      int v = base + li + e;
      if (anystop && ((v == s0) | (v == s1) | (v == s2) | (v == s3)))
        xp = BIG_NEG_F;
      if ((pm8 | om8) & (1u << e)) {
        xp = (xp > 0.0f) ? (xp * inv_rp) : (xp * rp);
        if ((om8 >> e) & 1u) {
          float cnt = 0.0f;
          unsigned int h = ((unsigned int)v * 2654435761u) >> 23;
          for (;;) {
            int k = hkey[h];
            if (k == -1) break;
            if (k == v) { cnt = (float)hval[h]; break; }
            h = (h + 1) & (HS1 - 1);
          }
          xp = xp - fp * cnt - pp;
        }
      }
      mx = fmaxf(mx, xp);
      esum += exp2f(xp * c2);
    }
  };

  processA(l0, A0, B0);
  processA(l1, A1, B1);
  processA(l2, A2, B2);
  if (v3) processA(l3, A3, B3);

  float ss = esum;
#pragma unroll
  for (int off = 32; off > 0; off >>= 1) ss += __shfl_down(ss, off, 64);
  if (lane == 0) wsum[wv] = ss;

  float srt = wave_sort64_desc(mx, lane);
  if (lane == 7) wtau[wv] = srt;   // wave's 8th-largest thread-max
  __syncthreads();

  if (tid == 0) {
    float tau = wtau[0];
#pragma unroll
    for (int w = 1; w < NT1 / 64; ++w) tau = fminf(tau, wtau[w]);
    tau_sh = ulp_down(tau, 16);
    float sacc = 0.0f;
#pragma unroll
    for (int w = 0; w < NT1 / 64; ++w) sacc += wsum[w];
    ws_sum[row * S + chunk] = sacc;
  }
  __syncthreads();
  const float taueff = tau_sh;

  // ---- phase B: re-stream; raw-filter, exact recompute, append to LDS ----
  A0 = *(const float4*)(lrow + l0); B0 = *(const float4*)(lrow + l0 + 4);
  A1 = *(const float4*)(lrow + l1); B1 = *(const float4*)(lrow + l1 + 4);
  A2 = *(const float4*)(lrow + l2); B2 = *(const float4*)(lrow + l2 + 4);
  if (v3) { A3 = *(const float4*)(lrow + l3); B3 = *(const float4*)(lrow + l3 + 4); }

  auto processB = [&](int li, float4 xa, float4 xb) {
    float xs[8] = {xa.x, xa.y, xa.z, xa.w, xb.x, xb.y, xb.z, xb.w};
#pragma unroll
    for (int e = 0; e < 8; ++e) {
      float x = xs[e];
      if (x >= taueff) {                 // raw >= penalized -> safe superset
        int v = base + li + e;
        int ll = li + e;
        if (anystop && ((v == s0) | (v == s1) | (v == s2) | (v == s3)))
          x = fminf(x, BIG_NEG_F);
        bool pm = (pbits[(unsigned)ll >> 5] >> ((unsigned)ll & 31u)) & 1u;
        bool om = (obits[(unsigned)ll >> 5] >> ((unsigned)ll & 31u)) & 1u;
        float cnt = 0.0f;
        if (om) {
          unsigned int h = ((unsigned int)v * 2654435761u) >> 23;
          for (;;) {
            int k = hkey[h];
            if (k == -1) break;
            if (k == v) { cnt = (float)hval[h]; break; }
            h = (h + 1) & (HS1 - 1);
          }
        }
        if (pm || om) x = (x > 0.0f) ? (x / rp) : (x * rp);
        x = x - fp * cnt;
        if (om) x = x - pp;
        if (x >= taueff) {
          float xd = x / t;              // exact reference finalist value
          int p = atomicAdd(&cnt_sh, 1);
          if (p < CAP) cand[p] = packkey(xd, v);
        }
      }
    }
  };

  processB(l0, A0, B0);
  processB(l1, A1, B1);
  processB(l2, A2, B2);
  if (v3) processB(l3, A3, B3);

  __syncthreads();
  int total = cnt_sh; if (total > CAP) total = CAP;
  for (int i = tid; i < CAP; i += NT1)
    if (i >= total) cand[i] = PAD_KEY;
  __syncthreads();

  // ---- exact sorted top-64 via register sorts + tournament ----
  unsigned long long rv = wave_sort64_desc_u64(cand[(wv << 6) + lane], lane);
  cand[(wv << 6) + lane] = rv;
  __syncthreads();

  if (wv < 4) {                               // 8 -> 4
    unsigned long long a = cand[((2 * wv) << 6) + lane];
    a = merge_top64(a, &cand[(2 * wv + 1) << 6], lane);
    mbuf[(wv << 6) + lane] = a;
  }
  __syncthreads();
  if (wv < 2) {                               // 4 -> 2
    unsigned long long a = mbuf[((2 * wv) << 6) + lane];
    a = merge_top64(a, &mbuf[(2 * wv + 1) << 6], lane);
    cand[(wv << 6) + lane] = a;
  }
  __syncthreads();
  if (wv == 0) {                              // 2 -> 1, write sorted run
    unsigned long long a = cand[lane];
    a = merge_top64(a, &cand[64], lane);
    ws_top[((size_t)row * S + chunk) * 64 + lane] = a;
  }
}

// ---------------- kernel 2: register-merge 8 runs + finalize ----------------
__global__ __launch_bounds__(NT2)
void k2_finalize(const float* __restrict__ temperature,
                 const int* __restrict__ top_k,
                 const float* __restrict__ top_p,
                 const float* __restrict__ noise,
                 const unsigned long long* __restrict__ ws_top,
                 const float* __restrict__ ws_sum,
                 float* __restrict__ out, int K)
{
#pragma clang fp contract(off)
  __shared__ unsigned long long buf[S * 64];
  __shared__ unsigned long long mbuf[4 * 64];
  __shared__ float sv[64];
  __shared__ int   si[64];
  __shared__ float se[64];
  __shared__ float gv[64];

  const int row  = blockIdx.x;
  const int tid  = threadIdx.x;
  const int lane = tid & 63;
  const int wv   = tid >> 6;      // 4 waves

  const float tmp = temperature[row];
  const float t   = (tmp < 1e-5f) ? 1.0f : tmp;
  const int   tk  = top_k[row];
  const float tpv = top_p[row];

  for (int i = tid; i < S * 64; i += NT2)
    buf[i] = ws_top[(size_t)row * S * 64 + i];
  __syncthreads();

  {                                           // 8 -> 4
    unsigned long long a = buf[((2 * wv) << 6) + lane];
    a = merge_top64(a, &buf[(2 * wv + 1) << 6], lane);
    mbuf[(wv << 6) + lane] = a;
  }
  __syncthreads();
  if (wv < 2) {                               // 4 -> 2
    unsigned long long a = mbuf[((2 * wv) << 6) + lane];
    a = merge_top64(a, &mbuf[(2 * wv + 1) << 6], lane);
    buf[(wv << 6) + lane] = a;
  }
  __syncthreads();
  if (wv == 0) {                              // 2 -> 1 + per-lane prep
    unsigned long long a = buf[lane];
    a = merge_top64(a, &buf[64], lane);
    float val = unpack_val(a);
    int   idx = unpack_idx(a);
    float m = __shfl(val, 0, 64);
    sv[lane] = val;
    si[lane] = idx;
    bool ok = (unsigned)idx < VV;
    float u = ok ? noise[(size_t)row * VV + idx] : 0.5f;
    float g = -logf(-logf(u));
    se[lane] = expf(val - m);
    gv[lane] = val / t + g;
  }
  __syncthreads();

  if (tid == 0) {
    float Ssum = 0.0f;
    for (int c = 0; c < S; c++) Ssum += ws_sum[row * S + c];
    const float m = sv[0];
    const float Z = Ssum * exp2f(-m * LOG2E);   // full-row softmax denominator

    int keff = (tk < 1) ? 64 : (tk < 64 ? tk : 64);

    float cum = 0.0f;
    int nk = 0;
    for (int j = 0; j < 64; j++) {
      if (j >= keff) break;
      if (!(cum < tpv)) break;
      nk++;
      cum += se[j] / Z;
    }

    float Zk = 0.0f;
    for (int j = 0; j < nk; j++) Zk += se[j];
    const float logZk = logf(Zk);

    float bv = -INFINITY; int bi = 0x7fffffff;
    for (int j = 0; j < nk; j++) {
      float val = gv[j];
      if (val > bv || (val == bv && si[j] < bi)) { bv = val; bi = si[j]; }
    }
    const int samp = (tmp < 1e-5f) ? si[0] : bi;
    out[row] = (float)samp;

    unsigned long long bm0 = 0ull, bm1 = 0ull;
    for (int j = 0; j < nk; j++) {
      int ix = si[j];
      if (ix < 64) bm0 |= 1ull << ix;
      else if (ix < 128) bm1 |= 1ull << (ix - 64);
    }
    int fi = 0;
    for (int j = 0; j < K; j++) {
      float lp; int ix;
      if (j < nk) {
        lp = (sv[j] - m) - logZk;
        ix = si[j];
      } else {
        while ((fi < 64) ? ((bm0 >> fi) & 1ull) : ((bm1 >> (fi - 64)) & 1ull)) fi++;
        ix = fi; fi++;
        lp = BIG_NEG_F;
      }
      out[NB + row * K + j]            = lp;
      out[NB + NB * K + row * K + j]   = (float)ix;
    }
  }
}

extern "C" void kernel_launch(void* const* d_in, const int* in_sizes, int n_in,
                              void* d_out, int out_size, void* d_ws, size_t ws_size,
                              hipStream_t stream) {
  const float* logits = (const float*)d_in[0];
  const int*   prompt = (const int*)d_in[1];
  const int*   outids = (const int*)d_in[2];
  const int*   stop   = (const int*)d_in[3];
  const int*   mint   = (const int*)d_in[4];
  const float* pres   = (const float*)d_in[5];
  const float* freq   = (const float*)d_in[6];
  const float* rep    = (const float*)d_in[7];
  const float* temp   = (const float*)d_in[8];
  const int*   topk   = (const int*)d_in[9];
  const float* topp   = (const float*)d_in[10];
  const float* noise  = (const float*)d_in[11];

  int B_ = in_sizes[4];                     // 128
  int K_ = (out_size - B_) / (2 * B_);      // 20

  unsigned long long* ws_top = (unsigned long long*)d_ws;          // NB*S*64 u64
  unsigned int* ws_pb = (unsigned int*)(ws_top + (size_t)NB * S * 64);
  unsigned int* ws_ob = ws_pb + (size_t)NB * GW;
  int* ws_hk = (int*)(ws_ob + (size_t)NB * GW);
  int* ws_hv = ws_hk + (size_t)NB * HS1;
  float* ws_sum = (float*)(ws_hv + (size_t)NB * HS1);

  k0_build<<<B_, NT0, 0, stream>>>(prompt, outids, ws_pb, ws_ob, ws_hk, ws_hv);
  dim3 g1(S, B_);
  k1_select<<<g1, NT1, 0, stream>>>(logits, stop, mint, pres, freq, rep, temp,
                                    ws_pb, ws_ob, ws_hk, ws_hv,
                                    ws_top, ws_sum);
  k2_finalize<<<B_, NT2, 0, stream>>>(temp, topk, topp, noise,
                                      ws_top, ws_sum, (float*)d_out, K_);
}